// Round 15
// baseline (144.283 us; speedup 1.0000x reference)
//
#include <hip/hip_runtime.h>
#include <math.h>

// CascadeGCN: 2-layer GCN, N=100000, E=2.5M, 5 -> 32 -> 1.
// R15 = R14 (best, 141.1us) + 1024-thread blocks on part/sorta/sortagg1:
// all three were grid-limited in block residency; doubling waves/block
// doubles resident waves/CU (part hits full 32 waves/CU) with LDS unchanged.
// sortagg1 aggregates at 4 threads/node (1024 = 4 x 256 nodes).
// Pipeline: memset(bcur) -> part -> sorta -> sortagg1 -> agg2.

#define NB_SHIFT  8          // 256 nodes per bucket
#define BNODES    256
#define NBK       512        // level-1 key space (nb = 391, padded)
#define CAP       8192       // bucket capacity (mean 6400, +22 sigma)
#define CAP_SHIFT 13
#define CHUNK     4888       // 512 chunks over E=2.5M -> exactly 2 blocks/CU
#define PBLK      1024       // 16 waves

// ---- LDS-staged bucket partition; packed 4 B records (dlow<<24 | src) ----
__global__ __launch_bounds__(PBLK) void k_part(const int* __restrict__ src,
                                               const int* __restrict__ dst, int E,
                                               int* __restrict__ bcur,
                                               int* __restrict__ pairs) {
    __shared__ int sp[CHUNK];                 // 19.6 KB records
    __shared__ unsigned short sb[CHUNK];      // 9.8 KB bucket ids
    __shared__ int cnt[NBK], ofs[NBK], cur[NBK], gbase[NBK];  // 8 KB
    int tid = threadIdx.x;
    int base = blockIdx.x * CHUNK;
    int m = min(CHUNK, E - base);

    if (tid < NBK) cnt[tid] = 0;
    __syncthreads();
    // pass 1: histogram (2x unrolled)
    for (int i = tid; i < m; i += 2 * PBLK) {
        int i1 = i + PBLK;
        int k0 = dst[base + i] >> NB_SHIFT;
        int k1 = (i1 < m) ? (dst[base + i1] >> NB_SHIFT) : -1;
        atomicAdd(&cnt[k0], 1);
        if (k1 >= 0) atomicAdd(&cnt[k1], 1);
    }
    __syncthreads();
    // exclusive scan over NBK keys (first 512 threads), Hillis-Steele
    int v = (tid < NBK) ? cnt[tid] : 0;
    if (tid < NBK) ofs[tid] = v;              // reuse ofs as scan buffer
    __syncthreads();
    for (int off = 1; off < NBK; off <<= 1) {
        int u = (tid < NBK && tid >= off) ? ofs[tid - off] : 0;
        __syncthreads();
        if (tid < NBK) ofs[tid] += u;
        __syncthreads();
    }
    if (tid < NBK) {
        int pre = ofs[tid] - v;               // exclusive prefix
        ofs[tid] = pre;
        cur[tid] = pre;
        gbase[tid] = (tid << CAP_SHIFT) + (v ? atomicAdd(&bcur[tid], v) : 0);
    }
    __syncthreads();
    // pass 2: bucket-ordered scatter into LDS (4x unrolled)
    for (int i = tid; i < m; i += 4 * PBLK) {
        int ia = i + PBLK, ib = i + 2 * PBLK, ic = i + 3 * PBLK;
        int s0 = src[base + i], d0 = dst[base + i];
        int s1 = 0, d1 = 0, s2 = 0, d2 = 0, s3 = 0, d3 = 0;
        if (ia < m) { s1 = src[base + ia]; d1 = dst[base + ia]; }
        if (ib < m) { s2 = src[base + ib]; d2 = dst[base + ib]; }
        if (ic < m) { s3 = src[base + ic]; d3 = dst[base + ic]; }
        int b0 = d0 >> NB_SHIFT;
        int p0 = atomicAdd(&cur[b0], 1);
        sp[p0] = ((d0 & (BNODES - 1)) << 24) | s0;
        sb[p0] = (unsigned short)b0;
        if (ia < m) {
            int b1 = d1 >> NB_SHIFT;
            int p1 = atomicAdd(&cur[b1], 1);
            sp[p1] = ((d1 & (BNODES - 1)) << 24) | s1;
            sb[p1] = (unsigned short)b1;
        }
        if (ib < m) {
            int b2 = d2 >> NB_SHIFT;
            int p2 = atomicAdd(&cur[b2], 1);
            sp[p2] = ((d2 & (BNODES - 1)) << 24) | s2;
            sb[p2] = (unsigned short)b2;
        }
        if (ic < m) {
            int b3 = d3 >> NB_SHIFT;
            int p3 = atomicAdd(&cur[b3], 1);
            sp[p3] = ((d3 & (BNODES - 1)) << 24) | s3;
            sb[p3] = (unsigned short)b3;
        }
    }
    __syncthreads();
    // coalesced-run writeout
    for (int i = tid; i < m; i += PBLK) {
        int b = sb[i];
        pairs[gbase[b] + (i - ofs[b])] = sp[i];
    }
}

// ---- per-bucket node histogram -> deg/nofs/dinv/xs ----
__global__ __launch_bounds__(1024) void k_sorta(const int* __restrict__ pairs,
                                                const int* __restrict__ bcur,
                                                const float* __restrict__ x,
                                                float* __restrict__ dinv,
                                                float* __restrict__ xs,
                                                int* __restrict__ nofs,
                                                int* __restrict__ deg, int n) {
    __shared__ int cnt[BNODES], scn[BNODES];
    int tid = threadIdx.x;
    int b = blockIdx.x;
    int base = b << CAP_SHIFT;
    int len = min(bcur[b], CAP);

    if (tid < BNODES) cnt[tid] = 0;
    __syncthreads();
    for (int i = tid; i < len; i += 1024)
        atomicAdd(&cnt[((unsigned)pairs[base + i]) >> 24], 1);
    __syncthreads();
    int v = (tid < BNODES) ? cnt[tid] : 0;
    if (tid < BNODES) scn[tid] = v;
    __syncthreads();
    for (int off = 1; off < BNODES; off <<= 1) {   // Hillis-Steele inclusive
        int u = (tid < BNODES && tid >= off) ? scn[tid - off] : 0;
        __syncthreads();
        if (tid < BNODES) scn[tid] += u;
        __syncthreads();
    }
    if (tid < BNODES) {
        int node = (b << NB_SHIFT) + tid;
        if (node < n) {
            nofs[node] = base + scn[tid] - v;      // exclusive
            deg[node] = v;
            float di = rsqrtf((float)v + 1.0f);
            dinv[node] = di;
            const float* xr = x + (size_t)node * 5;
            float* xo = xs + ((size_t)node << 3);  // padded row: 8 floats
#pragma unroll
            for (int k = 0; k < 5; ++k) xo[k] = xr[k] * di;
        }
    }
}

// ---- LDS counting sort + fused layer-1 aggregation + sorted writeback ----
__global__ __launch_bounds__(1024) void k_sortagg1(int* __restrict__ pairs,
                                                   const int* __restrict__ bcur,
                                                   const int* __restrict__ nofs,
                                                   const int* __restrict__ deg,
                                                   const float* __restrict__ xs,
                                                   const float* __restrict__ dinv,
                                                   const float* __restrict__ W1,
                                                   const float* __restrict__ b1,
                                                   const float* __restrict__ W2,
                                                   float* __restrict__ h2s, int n) {
    __shared__ int stage2[CAP];               // 32 KB: node-sorted src ids
    __shared__ int ofs[BNODES], cnt[BNODES], cur[BNODES];   // 3 KB
    __shared__ float w1[160], bb1[32], w2[32];
    int tid = threadIdx.x;
    int b = blockIdx.x;
    int nbase = b << NB_SHIFT;
    int base = b << CAP_SHIFT;
    int len = min(bcur[b], CAP);

    if (tid < 160) w1[tid] = W1[tid];
    else if (tid < 192) bb1[tid - 160] = b1[tid - 160];
    else if (tid < 224) w2[tid - 192] = W2[tid - 192];
    if (tid < BNODES) {
        int node = nbase + tid;
        int o = 0, c = 0;
        if (node < n) { o = nofs[node] - base; c = deg[node]; }
        ofs[tid] = o; cnt[tid] = c; cur[tid] = o;
    }
    __syncthreads();
    // counting-sort scatter into LDS (4x unrolled, stride 4096)
    for (int i = tid; i < len; i += 4096) {
        int ia = i + 1024, ib = i + 2048, ic = i + 3072;
        int v0 = pairs[base + i];
        int v1 = (ia < len) ? pairs[base + ia] : -1;
        int v2 = (ib < len) ? pairs[base + ib] : -1;
        int v3 = (ic < len) ? pairs[base + ic] : -1;
        int p0 = atomicAdd(&cur[((unsigned)v0) >> 24], 1);
        stage2[p0] = v0 & 0x00FFFFFF;
        if (v1 != -1) {
            int p1 = atomicAdd(&cur[((unsigned)v1) >> 24], 1);
            stage2[p1] = v1 & 0x00FFFFFF;
        }
        if (v2 != -1) {
            int p2 = atomicAdd(&cur[((unsigned)v2) >> 24], 1);
            stage2[p2] = v2 & 0x00FFFFFF;
        }
        if (v3 != -1) {
            int p3 = atomicAdd(&cur[((unsigned)v3) >> 24], 1);
            stage2[p3] = v3 & 0x00FFFFFF;
        }
    }
    __syncthreads();
    // sorted writeback for agg2 — int4 vectorized (base 32KB-aligned)
    {
        int len4 = len >> 2;                  // whole int4s
        const int4* s4 = (const int4*)stage2;
        int4* p4 = (int4*)(pairs + base);
        for (int i = tid; i < len4; i += 1024) p4[i] = s4[i];
        for (int i = (len4 << 2) + tid; i < len; i += 1024)
            pairs[base + i] = stage2[i];
    }
    // layer-1 aggregation straight from LDS: 4 threads per node
    int t4 = tid >> 2, q = tid & 3;
    int node = nbase + t4;
    if (node >= n) return;
    int beg = ofs[t4], dg = cnt[t4];
    float a0 = 0.f, a1 = 0.f, a2 = 0.f, a3 = 0.f, a4 = 0.f;
    if (!q) {                                 // self-loop term
        const float* xo = xs + ((size_t)node << 3);
        a0 = xo[0]; a1 = xo[1]; a2 = xo[2]; a3 = xo[3]; a4 = xo[4];
    }
    for (int e = beg + q; e < beg + dg; e += 4) {
        int s = stage2[e];
        const float* xr = xs + ((size_t)s << 3);
        float4 qq = *(const float4*)xr;
        float q4 = xr[4];
        a0 += qq.x; a1 += qq.y; a2 += qq.z; a3 += qq.w; a4 += q4;
    }
    a0 += __shfl_xor(a0, 1); a1 += __shfl_xor(a1, 1); a2 += __shfl_xor(a2, 1);
    a3 += __shfl_xor(a3, 1); a4 += __shfl_xor(a4, 1);
    a0 += __shfl_xor(a0, 2); a1 += __shfl_xor(a1, 2); a2 += __shfl_xor(a2, 2);
    a3 += __shfl_xor(a3, 2); a4 += __shfl_xor(a4, 2);
    if (q) return;
    float di = dinv[node];
    a0 *= di; a1 *= di; a2 *= di; a3 *= di; a4 *= di;
    float sum = 0.f;
#pragma unroll
    for (int c = 0; c < 32; ++c) {
        float z = bb1[c] + a0 * w1[c] + a1 * w1[32 + c] + a2 * w1[64 + c]
                         + a3 * w1[96 + c] + a4 * w1[128 + c];
        sum += fmaxf(z, 0.f) * w2[c];
    }
    h2s[node] = sum * di;                     // pre-scale by source dinv
}

// ---- layer-2: register accumulation + sigmoid, 4 threads/node ----
__global__ __launch_bounds__(256) void k_agg2(const int* __restrict__ pairs,
                                              const int* __restrict__ nofs,
                                              const int* __restrict__ deg,
                                              const float* __restrict__ h2s,
                                              const float* __restrict__ dinv,
                                              const float* __restrict__ b2,
                                              float* __restrict__ out, int n) {
    int tid = threadIdx.x;
    int node = blockIdx.x * 64 + (tid >> 2);
    int q = tid & 3;
    if (node >= n) return;
    int beg = nofs[node], dg = deg[node];
    float a = 0.f;
    for (int e = beg + q; e < beg + dg; e += 4) a += h2s[pairs[e]];
    a += __shfl_xor(a, 1);
    a += __shfl_xor(a, 2);
    if (q) return;
    float v = dinv[node] * (a + h2s[node]) + b2[0];
    out[node] = 1.0f / (1.0f + __expf(-v));
}

extern "C" void kernel_launch(void* const* d_in, const int* in_sizes, int n_in,
                              void* d_out, int out_size, void* d_ws, size_t ws_size,
                              hipStream_t stream) {
    const float* x  = (const float*)d_in[0];
    const int*   ei = (const int*)d_in[1];
    const float* W1 = (const float*)d_in[2];
    const float* b1 = (const float*)d_in[3];
    const float* W2 = (const float*)d_in[4];
    const float* b2 = (const float*)d_in[5];
    float* out = (float*)d_out;

    const int n = in_sizes[0] / 5;       // 100000
    const int E = in_sizes[1] / 2;       // 2500000
    const int* src = ei;
    const int* dst = ei + E;
    const int nb = (n + BNODES - 1) >> NB_SHIFT;   // 391

    // ws (4B units, 16B-aligned):
    // [pairs (nb+1)<<13][nofs n][deg n][dinv n][h2s n][xs 8n][bcur NBK]
    int* wsi = (int*)d_ws;
    int*   pairs = wsi;
    int*   nofs  = wsi + ((size_t)(nb + 1) << CAP_SHIFT);
    int*   deg   = nofs + n;
    float* dinv  = (float*)(deg + n);
    float* h2s   = dinv + n;
    float* xs    = h2s + n;
    int*   bcur  = (int*)(xs + (size_t)8 * n);

    const int nchunk = (E + CHUNK - 1) / CHUNK;    // 512
    const int nagg   = (n + 63) / 64;              // 1563

    hipMemsetAsync(bcur, 0, NBK * sizeof(int), stream);
    k_part<<<nchunk, PBLK, 0, stream>>>(src, dst, E, bcur, pairs);
    k_sorta<<<nb, 1024, 0, stream>>>(pairs, bcur, x, dinv, xs, nofs, deg, n);
    k_sortagg1<<<nb, 1024, 0, stream>>>(pairs, bcur, nofs, deg, xs, dinv,
                                        W1, b1, W2, h2s, n);
    k_agg2<<<nagg, 256, 0, stream>>>(pairs, nofs, deg, h2s, dinv, b2, out, n);
}

// Round 16
// 139.894 us; speedup vs baseline: 1.0314x; 1.0314x over previous
//
#include <hip/hip_runtime.h>
#include <math.h>

// CascadeGCN: 2-layer GCN, N=100000, E=2.5M, 5 -> 32 -> 1.
// R16 = R14 exact revert (best measured, 141.1us). R15's 1024-thread blocks
// regressed (barrier cost on partially-active scan phases); R12/R15 bracket
// the config space — this is the local optimum.
// Structure: two-level LDS counting sort (512 chunk-partition blocks ->
// 391 x 256-node buckets) + fused sort/layer-1 kernel + layer-2 gather.
// All aggregation is register-accumulated over contiguous per-node runs;
// no global float atomics anywhere; LDS atomics only where contention is
// near-zero (random keys).
// Pipeline: memset(bcur) -> part -> sorta -> sortagg1 -> agg2.

#define NB_SHIFT  8          // 256 nodes per bucket
#define BNODES    256
#define NBK       512        // level-1 key space (nb = 391, padded)
#define CAP       8192       // bucket capacity (mean 6400, +22 sigma)
#define CAP_SHIFT 13
#define CHUNK     4888       // 512 chunks over E=2.5M -> exactly 2 blocks/CU
#define PBLK      512        // 8 waves

// ---- LDS-staged bucket partition; packed 4 B records (dlow<<24 | src) ----
__global__ __launch_bounds__(PBLK) void k_part(const int* __restrict__ src,
                                               const int* __restrict__ dst, int E,
                                               int* __restrict__ bcur,
                                               int* __restrict__ pairs) {
    __shared__ int sp[CHUNK];                 // 19.6 KB records
    __shared__ unsigned short sb[CHUNK];      // 9.8 KB bucket ids
    __shared__ int cnt[NBK], ofs[NBK], cur[NBK], gbase[NBK];  // 8 KB
    int tid = threadIdx.x;
    int base = blockIdx.x * CHUNK;
    int m = min(CHUNK, E - base);

    if (tid < NBK) cnt[tid] = 0;
    __syncthreads();
    // pass 1: histogram (2x unrolled)
    for (int i = tid; i < m; i += 2 * PBLK) {
        int i1 = i + PBLK;
        int k0 = dst[base + i] >> NB_SHIFT;
        int k1 = (i1 < m) ? (dst[base + i1] >> NB_SHIFT) : -1;
        atomicAdd(&cnt[k0], 1);
        if (k1 >= 0) atomicAdd(&cnt[k1], 1);
    }
    __syncthreads();
    // exclusive scan: one bucket per thread (PBLK == NBK), Hillis-Steele
    int v = cnt[tid];
    ofs[tid] = v;                             // reuse ofs as scan buffer
    __syncthreads();
    for (int off = 1; off < NBK; off <<= 1) {
        int u = (tid >= off) ? ofs[tid - off] : 0;
        __syncthreads();
        ofs[tid] += u;
        __syncthreads();
    }
    int pre = ofs[tid] - v;                   // exclusive prefix
    ofs[tid] = pre;
    cur[tid] = pre;
    gbase[tid] = (tid << CAP_SHIFT) + (v ? atomicAdd(&bcur[tid], v) : 0);
    __syncthreads();
    // pass 2: bucket-ordered scatter into LDS (4x unrolled)
    for (int i = tid; i < m; i += 4 * PBLK) {
        int ia = i + PBLK, ib = i + 2 * PBLK, ic = i + 3 * PBLK;
        int s0 = src[base + i], d0 = dst[base + i];
        int s1 = 0, d1 = 0, s2 = 0, d2 = 0, s3 = 0, d3 = 0;
        if (ia < m) { s1 = src[base + ia]; d1 = dst[base + ia]; }
        if (ib < m) { s2 = src[base + ib]; d2 = dst[base + ib]; }
        if (ic < m) { s3 = src[base + ic]; d3 = dst[base + ic]; }
        int b0 = d0 >> NB_SHIFT;
        int p0 = atomicAdd(&cur[b0], 1);
        sp[p0] = ((d0 & (BNODES - 1)) << 24) | s0;
        sb[p0] = (unsigned short)b0;
        if (ia < m) {
            int b1 = d1 >> NB_SHIFT;
            int p1 = atomicAdd(&cur[b1], 1);
            sp[p1] = ((d1 & (BNODES - 1)) << 24) | s1;
            sb[p1] = (unsigned short)b1;
        }
        if (ib < m) {
            int b2 = d2 >> NB_SHIFT;
            int p2 = atomicAdd(&cur[b2], 1);
            sp[p2] = ((d2 & (BNODES - 1)) << 24) | s2;
            sb[p2] = (unsigned short)b2;
        }
        if (ic < m) {
            int b3 = d3 >> NB_SHIFT;
            int p3 = atomicAdd(&cur[b3], 1);
            sp[p3] = ((d3 & (BNODES - 1)) << 24) | s3;
            sb[p3] = (unsigned short)b3;
        }
    }
    __syncthreads();
    // coalesced-run writeout
    for (int i = tid; i < m; i += PBLK) {
        int b = sb[i];
        pairs[gbase[b] + (i - ofs[b])] = sp[i];
    }
}

// ---- per-bucket node histogram -> deg/nofs/dinv/xs ----
__global__ __launch_bounds__(512) void k_sorta(const int* __restrict__ pairs,
                                               const int* __restrict__ bcur,
                                               const float* __restrict__ x,
                                               float* __restrict__ dinv,
                                               float* __restrict__ xs,
                                               int* __restrict__ nofs,
                                               int* __restrict__ deg, int n) {
    __shared__ int cnt[BNODES], scn[BNODES];
    int tid = threadIdx.x;
    int b = blockIdx.x;
    int base = b << CAP_SHIFT;
    int len = min(bcur[b], CAP);

    if (tid < BNODES) cnt[tid] = 0;
    __syncthreads();
    for (int i = tid; i < len; i += 512)
        atomicAdd(&cnt[((unsigned)pairs[base + i]) >> 24], 1);
    __syncthreads();
    int v = (tid < BNODES) ? cnt[tid] : 0;
    if (tid < BNODES) scn[tid] = v;
    __syncthreads();
    for (int off = 1; off < BNODES; off <<= 1) {   // Hillis-Steele inclusive
        int u = (tid < BNODES && tid >= off) ? scn[tid - off] : 0;
        __syncthreads();
        if (tid < BNODES) scn[tid] += u;
        __syncthreads();
    }
    if (tid < BNODES) {
        int node = (b << NB_SHIFT) + tid;
        if (node < n) {
            nofs[node] = base + scn[tid] - v;      // exclusive
            deg[node] = v;
            float di = rsqrtf((float)v + 1.0f);
            dinv[node] = di;
            const float* xr = x + (size_t)node * 5;
            float* xo = xs + ((size_t)node << 3);  // padded row: 8 floats
#pragma unroll
            for (int k = 0; k < 5; ++k) xo[k] = xr[k] * di;
        }
    }
}

// ---- LDS counting sort + fused layer-1 aggregation + sorted writeback ----
__global__ __launch_bounds__(512) void k_sortagg1(int* __restrict__ pairs,
                                                  const int* __restrict__ bcur,
                                                  const int* __restrict__ nofs,
                                                  const int* __restrict__ deg,
                                                  const float* __restrict__ xs,
                                                  const float* __restrict__ dinv,
                                                  const float* __restrict__ W1,
                                                  const float* __restrict__ b1,
                                                  const float* __restrict__ W2,
                                                  float* __restrict__ h2s, int n) {
    __shared__ int stage2[CAP];               // 32 KB: node-sorted src ids
    __shared__ int ofs[BNODES], cnt[BNODES], cur[BNODES];   // 3 KB
    __shared__ float w1[160], bb1[32], w2[32];
    int tid = threadIdx.x;
    int b = blockIdx.x;
    int nbase = b << NB_SHIFT;
    int base = b << CAP_SHIFT;
    int len = min(bcur[b], CAP);

    if (tid < 160) w1[tid] = W1[tid];
    else if (tid < 192) bb1[tid - 160] = b1[tid - 160];
    else if (tid < 224) w2[tid - 192] = W2[tid - 192];
    if (tid < BNODES) {
        int node = nbase + tid;
        int o = 0, c = 0;
        if (node < n) { o = nofs[node] - base; c = deg[node]; }
        ofs[tid] = o; cnt[tid] = c; cur[tid] = o;
    }
    __syncthreads();
    // counting-sort scatter into LDS (4x unrolled)
    for (int i = tid; i < len; i += 2048) {
        int ia = i + 512, ib = i + 1024, ic = i + 1536;
        int v0 = pairs[base + i];
        int v1 = (ia < len) ? pairs[base + ia] : -1;
        int v2 = (ib < len) ? pairs[base + ib] : -1;
        int v3 = (ic < len) ? pairs[base + ic] : -1;
        int p0 = atomicAdd(&cur[((unsigned)v0) >> 24], 1);
        stage2[p0] = v0 & 0x00FFFFFF;
        if (v1 != -1) {
            int p1 = atomicAdd(&cur[((unsigned)v1) >> 24], 1);
            stage2[p1] = v1 & 0x00FFFFFF;
        }
        if (v2 != -1) {
            int p2 = atomicAdd(&cur[((unsigned)v2) >> 24], 1);
            stage2[p2] = v2 & 0x00FFFFFF;
        }
        if (v3 != -1) {
            int p3 = atomicAdd(&cur[((unsigned)v3) >> 24], 1);
            stage2[p3] = v3 & 0x00FFFFFF;
        }
    }
    __syncthreads();
    // sorted writeback for agg2 — int4 vectorized (base 32KB-aligned)
    {
        int len4 = len >> 2;                  // whole int4s
        const int4* s4 = (const int4*)stage2;
        int4* p4 = (int4*)(pairs + base);
        for (int i = tid; i < len4; i += 512) p4[i] = s4[i];
        for (int i = (len4 << 2) + tid; i < len; i += 512)
            pairs[base + i] = stage2[i];
    }
    // layer-1 aggregation straight from LDS: 2 threads per node
    int t2 = tid >> 1, half = tid & 1;
    int node = nbase + t2;
    if (node >= n) return;
    int beg = ofs[t2], dg = cnt[t2];
    float a0 = 0.f, a1 = 0.f, a2 = 0.f, a3 = 0.f, a4 = 0.f;
    if (!half) {                              // self-loop term
        const float* xo = xs + ((size_t)node << 3);
        a0 = xo[0]; a1 = xo[1]; a2 = xo[2]; a3 = xo[3]; a4 = xo[4];
    }
    for (int e = beg + half; e < beg + dg; e += 2) {
        int s = stage2[e];
        const float* xr = xs + ((size_t)s << 3);
        float4 q = *(const float4*)xr;
        float q4 = xr[4];
        a0 += q.x; a1 += q.y; a2 += q.z; a3 += q.w; a4 += q4;
    }
    a0 += __shfl_xor(a0, 1); a1 += __shfl_xor(a1, 1); a2 += __shfl_xor(a2, 1);
    a3 += __shfl_xor(a3, 1); a4 += __shfl_xor(a4, 1);
    if (half) return;
    float di = dinv[node];
    a0 *= di; a1 *= di; a2 *= di; a3 *= di; a4 *= di;
    float sum = 0.f;
#pragma unroll
    for (int c = 0; c < 32; ++c) {
        float z = bb1[c] + a0 * w1[c] + a1 * w1[32 + c] + a2 * w1[64 + c]
                         + a3 * w1[96 + c] + a4 * w1[128 + c];
        sum += fmaxf(z, 0.f) * w2[c];
    }
    h2s[node] = sum * di;                     // pre-scale by source dinv
}

// ---- layer-2: register accumulation + sigmoid, 4 threads/node ----
__global__ __launch_bounds__(256) void k_agg2(const int* __restrict__ pairs,
                                              const int* __restrict__ nofs,
                                              const int* __restrict__ deg,
                                              const float* __restrict__ h2s,
                                              const float* __restrict__ dinv,
                                              const float* __restrict__ b2,
                                              float* __restrict__ out, int n) {
    int tid = threadIdx.x;
    int node = blockIdx.x * 64 + (tid >> 2);
    int q = tid & 3;
    if (node >= n) return;
    int beg = nofs[node], dg = deg[node];
    float a = 0.f;
    for (int e = beg + q; e < beg + dg; e += 4) a += h2s[pairs[e]];
    a += __shfl_xor(a, 1);
    a += __shfl_xor(a, 2);
    if (q) return;
    float v = dinv[node] * (a + h2s[node]) + b2[0];
    out[node] = 1.0f / (1.0f + __expf(-v));
}

extern "C" void kernel_launch(void* const* d_in, const int* in_sizes, int n_in,
                              void* d_out, int out_size, void* d_ws, size_t ws_size,
                              hipStream_t stream) {
    const float* x  = (const float*)d_in[0];
    const int*   ei = (const int*)d_in[1];
    const float* W1 = (const float*)d_in[2];
    const float* b1 = (const float*)d_in[3];
    const float* W2 = (const float*)d_in[4];
    const float* b2 = (const float*)d_in[5];
    float* out = (float*)d_out;

    const int n = in_sizes[0] / 5;       // 100000
    const int E = in_sizes[1] / 2;       // 2500000
    const int* src = ei;
    const int* dst = ei + E;
    const int nb = (n + BNODES - 1) >> NB_SHIFT;   // 391

    // ws (4B units, 16B-aligned):
    // [pairs (nb+1)<<13][nofs n][deg n][dinv n][h2s n][xs 8n][bcur NBK]
    int* wsi = (int*)d_ws;
    int*   pairs = wsi;
    int*   nofs  = wsi + ((size_t)(nb + 1) << CAP_SHIFT);
    int*   deg   = nofs + n;
    float* dinv  = (float*)(deg + n);
    float* h2s   = dinv + n;
    float* xs    = h2s + n;
    int*   bcur  = (int*)(xs + (size_t)8 * n);

    const int nchunk = (E + CHUNK - 1) / CHUNK;    // 512
    const int nagg   = (n + 63) / 64;              // 1563

    hipMemsetAsync(bcur, 0, NBK * sizeof(int), stream);
    k_part<<<nchunk, PBLK, 0, stream>>>(src, dst, E, bcur, pairs);
    k_sorta<<<nb, 512, 0, stream>>>(pairs, bcur, x, dinv, xs, nofs, deg, n);
    k_sortagg1<<<nb, 512, 0, stream>>>(pairs, bcur, nofs, deg, xs, dinv,
                                       W1, b1, W2, h2s, n);
    k_agg2<<<nagg, 256, 0, stream>>>(pairs, nofs, deg, h2s, dinv, b2, out, n);
}